// Round 8
// baseline (352.842 us; speedup 1.0000x reference)
//
#include <hip/hip_runtime.h>
#include <hip/hip_bf16.h>

// Problem constants
#define TSEQ   1024
#define NC     1024          // C
#define MBT    4096          // B*T
#define NEXP   8
#define NHEAD  16
#define DHEAD  64
#define PERM_CAP 10240       // 8192 pairs + 16 groups * 128 pad
#define MAXTILES 96

typedef __attribute__((ext_vector_type(8))) short bf16x8;
typedef __attribute__((ext_vector_type(4))) float f32x4;

typedef __attribute__((address_space(3))) unsigned char* lds_ptr_t;
typedef const __attribute__((address_space(1))) unsigned char* glb_ptr_t;

// async global->LDS DMA, 16B per lane, dest = wave-uniform base + lane*16
static __device__ __forceinline__ void gload16(const void* g, void* l){
    __builtin_amdgcn_global_load_lds((glb_ptr_t)g, (lds_ptr_t)l, 16, 0, 0);
}

// RNE fp32->bf16 (values are finite/normal here; no NaN path needed)
static __device__ __forceinline__ unsigned short f2bf(float x){
    unsigned int u = __float_as_uint(x);
    u += 0x7fff + ((u >> 16) & 1);
    return (unsigned short)(u >> 16);
}
static __device__ __forceinline__ unsigned int pk2bf(float a, float b){
    unsigned int ua = __float_as_uint(a), ub = __float_as_uint(b);
    ua += 0x7fff + ((ua >> 16) & 1);
    ub += 0x7fff + ((ub >> 16) & 1);
    return (ua >> 16) | (ub & 0xffff0000u);
}
static __device__ __forceinline__ float bf2f(unsigned short u){
    return __uint_as_float(((unsigned int)u) << 16);
}

// ---------------------------------------------------------------------------
// prep_gate: z<18 -> weight transpose+cvt slices; z==18 -> gate (4 tokens/blk)
// ---------------------------------------------------------------------------
__global__ __launch_bounds__(256)
void prep_gate(const float* __restrict__ Wk, const float* __restrict__ Wv,
               const float* __restrict__ Wq, const float* __restrict__ Wo,
               unsigned short* __restrict__ Wkvt, unsigned short* __restrict__ Wqt,
               unsigned short* __restrict__ Wot,
               const float* __restrict__ x, const float* __restrict__ noise,
               const float* __restrict__ Wg, const float* __restrict__ Wn,
               int* __restrict__ epair, float* __restrict__ wpair,
               unsigned short* __restrict__ xb){
    int z = blockIdx.z;
    int tx = threadIdx.x, ty = threadIdx.y;
    if (z < 18){
        __shared__ float t[32][33];
        const float* src; unsigned short* dst;
        if (z == 0){ src = Wk; dst = Wkvt; }
        else if (z == 1){ src = Wv; dst = Wkvt + (size_t)NC*NC; }
        else if (z < 10){ src = Wq + (size_t)(z-2)*NC*NC; dst = Wqt + (size_t)(z-2)*NC*NC; }
        else { src = Wo + (size_t)(z-10)*NC*NC; dst = Wot + (size_t)(z-10)*NC*NC; }
        int k0 = blockIdx.x * 32, n0 = blockIdx.y * 32;
        #pragma unroll
        for (int i = 0; i < 4; i++)
            t[ty + i*8][tx] = src[(size_t)(k0 + ty + i*8)*NC + n0 + tx];
        __syncthreads();
        #pragma unroll
        for (int i = 0; i < 4; i++)
            dst[(size_t)(n0 + ty + i*8)*NC + k0 + tx] = f2bf(t[tx][ty + i*8]);
        return;
    }
    // gate path
    int flat = ty*32 + tx;
    int blk = blockIdx.y*32 + blockIdx.x;        // 0..1023
    int t = blk*4 + (flat >> 6);
    int lane = flat & 63;
    float ag[8] = {0,0,0,0,0,0,0,0};
    float an[8] = {0,0,0,0,0,0,0,0};
    const float* xr = x + (size_t)t * NC;
    unsigned short* xbr = xb + (size_t)t * NC;
    for (int c = lane; c < NC; c += 64){
        float xv = xr[c];
        xbr[c] = f2bf(xv);
        #pragma unroll
        for (int j = 0; j < 8; j++){
            ag[j] = fmaf(xv, Wg[c*8 + j], ag[j]);
            an[j] = fmaf(xv, Wn[c*8 + j], an[j]);
        }
    }
    #pragma unroll
    for (int j = 0; j < 8; j++){
        #pragma unroll
        for (int o = 32; o >= 1; o >>= 1){
            ag[j] += __shfl_xor(ag[j], o, 64);
            an[j] += __shfl_xor(an[j], o, 64);
        }
    }
    if (lane == 0){
        float lg[8];
        #pragma unroll
        for (int j = 0; j < 8; j++){
            float z2 = an[j];
            float sp = (z2 > 20.f) ? z2 : log1pf(expf(z2));
            lg[j] = ag[j] + noise[(size_t)t*8 + j] * sp;
        }
        int i0 = 0; float v0 = lg[0];
        #pragma unroll
        for (int j = 1; j < 8; j++) if (lg[j] > v0){ v0 = lg[j]; i0 = j; }
        int i1 = -1; float v1 = -3.4e38f;
        #pragma unroll
        for (int j = 0; j < 8; j++) if (j != i0 && lg[j] > v1){ v1 = lg[j]; i1 = j; }
        float e1 = expf(v1 - v0);
        float w0 = 1.f / (1.f + e1);
        epair[2*t]   = i0;
        epair[2*t+1] = i1;
        wpair[2*t]   = w0;
        wpair[2*t+1] = e1 * w0;
    }
}

// ---------------------------------------------------------------------------
// Grouping
// ---------------------------------------------------------------------------
__global__ void group_build(const int* __restrict__ epair, int* __restrict__ cursor,
                            int* __restrict__ tile_g, int* __restrict__ tile_pos,
                            int* __restrict__ ntiles, int* __restrict__ perm){
    __shared__ int cnt[16];
    int tid = threadIdx.x;
    if (tid < 16) cnt[tid] = 0;
    __syncthreads();
    for (int p = tid; p < 2*MBT; p += 256){
        int g = ((p & 1) << 3) | epair[p];
        atomicAdd(&cnt[g], 1);
    }
    for (int i = tid; i < PERM_CAP; i += 256) perm[i] = -1;
    __syncthreads();
    if (tid == 0){
        int off = 0, tt = 0;
        for (int g = 0; g < 16; g++){
            int c = cnt[g];
            cursor[g] = off;
            int nt = (c + 127) >> 7;
            for (int i = 0; i < nt; i++){ tile_g[tt] = g; tile_pos[tt] = off + i*128; tt++; }
            off += nt << 7;
        }
        ntiles[0] = tt;
    }
}

// wave-aggregated scatter: one atomic per (wave, group) instead of per thread
__global__ __launch_bounds__(256)
void fill_perm(const int* __restrict__ epair, int* __restrict__ cursor,
               int* __restrict__ perm){
    int p = blockIdx.x * 256 + threadIdx.x;      // 32 blocks x 256 = 8192
    int lane = threadIdx.x & 63;
    int g = ((p & 1) << 3) | epair[p];
    unsigned long long ltmask = (lane == 63) ? 0x7fffffffffffffffull
                                             : (((unsigned long long)1 << lane) - 1);
    #pragma unroll 1
    for (int grp = 0; grp < 16; grp++){
        unsigned long long m = __ballot(g == grp);
        if (m == 0ull) continue;
        if (g == grp){
            int leader = __ffsll(m) - 1;
            int base = 0;
            if (lane == leader) base = atomicAdd(&cursor[grp], __popcll(m));
            base = __shfl(base, leader, 64);
            perm[base + __popcll(m & ltmask)] = p;
        }
    }
}

// ---------------------------------------------------------------------------
// Fused KV + Q GEMM with DOUBLE-BUFFERED DMA staging (1 barrier / K-iter).
// Blocks [0,512): KV (ntile<8 -> K into kbuf; ntile>=8 -> V^T into vbufT).
// Blocks [512,1280): grouped Q.  128x128 tile, BK=64, XOR swizzle.
// ---------------------------------------------------------------------------
#define AB 8192   // one staging buffer: 128 rows x 64 ushorts

__global__ __launch_bounds__(256)
void gemm_fused(const unsigned short* __restrict__ xb,
                const unsigned short* __restrict__ Wkvt,
                const unsigned short* __restrict__ Wqt,
                unsigned short* __restrict__ kbuf,
                unsigned short* __restrict__ vbT,
                unsigned short* __restrict__ qselb,
                const int* __restrict__ perm,
                const int* __restrict__ tile_g,
                const int* __restrict__ tile_pos,
                const int* __restrict__ ntiles){
    int flat = blockIdx.x;
    bool isQ = (flat >= 512);
    int ntile, slot, tpos = 0;
    const unsigned short* bt;
    if (!isQ){
        ntile = flat & 15; slot = flat >> 4;
        bt = Wkvt;
    } else {
        int f2 = flat - 512;
        ntile = f2 & 7; slot = f2 >> 3;
        if (slot >= ntiles[0]) return;
        int g = tile_g[slot];
        bt = Wqt + (size_t)(g & 7) * NC * NC;
        tpos = tile_pos[slot];
    }

    __shared__ __align__(16) unsigned short smem[4*AB];   // 64 KB: dbuf A/B
    int tid = threadIdx.x;
    int lane = tid & 63, wv = tid >> 6;
    int wr = wv >> 1, wc = wv & 1;
    int quad = lane >> 4, l15 = lane & 15;

    int laneR = lane >> 3;
    int swz = ((lane & 7) ^ (laneR & 7)) * 8;

    const unsigned short* ag[4];
    const unsigned short* bg[4];
    #pragma unroll
    for (int it = 0; it < 4; it++){
        int row = wv*32 + it*8 + laneR;
        if (!isQ){
            ag[it] = xb + (size_t)(slot*128 + row) * NC + swz;
        } else {
            int p = perm[tpos + row];
            if (p < 0) p = 0;                // harmless: C row discarded at store
            ag[it] = xb + (size_t)(p >> 1) * NC + swz;
        }
        bg[it] = bt + (size_t)(ntile*128 + row) * NC + swz;
    }

    f32x4 acc[4][4];
    #pragma unroll
    for (int i = 0; i < 4; i++)
        #pragma unroll
        for (int j = 0; j < 4; j++) acc[i][j] = (f32x4){0.f,0.f,0.f,0.f};

    // prologue: issue K-block 0 into buf 0
    #pragma unroll
    for (int it = 0; it < 4; it++){
        gload16(ag[it], &smem[(wv*32 + it*8)*64]);
        gload16(bg[it], &smem[AB + (wv*32 + it*8)*64]);
    }
    int cur = 0;
    for (int kk = 0; kk < NC; kk += 64){
        __syncthreads();                       // buf[cur] ready; buf[cur^1] free
        if (kk + 64 < NC){
            int nb = (cur ^ 1) * 2 * AB;
            #pragma unroll
            for (int it = 0; it < 4; it++){
                gload16(ag[it] + kk + 64, &smem[nb + (wv*32 + it*8)*64]);
                gload16(bg[it] + kk + 64, &smem[nb + AB + (wv*32 + it*8)*64]);
            }
        }
        const unsigned short* As = &smem[cur*2*AB];
        const unsigned short* Bs = &smem[cur*2*AB + AB];
        #pragma unroll
        for (int kh = 0; kh < 2; kh++){
            bf16x8 af[4], bfr[4];
            #pragma unroll
            for (int mi = 0; mi < 4; mi++)
                af[mi]  = *(const bf16x8*)&As[(wr*64 + mi*16 + l15)*64 + (((kh*4 + quad) ^ (l15 & 7))*8)];
            #pragma unroll
            for (int ni = 0; ni < 4; ni++)
                bfr[ni] = *(const bf16x8*)&Bs[(wc*64 + ni*16 + l15)*64 + (((kh*4 + quad) ^ (l15 & 7))*8)];
            #pragma unroll
            for (int mi = 0; mi < 4; mi++)
                #pragma unroll
                for (int ni = 0; ni < 4; ni++)
                    acc[mi][ni] = __builtin_amdgcn_mfma_f32_16x16x32_bf16(af[mi], bfr[ni], acc[mi][ni], 0, 0, 0);
        }
        cur ^= 1;
    }
    __syncthreads();                           // smem free for bounce

    bool isV = (!isQ) && (ntile >= 8);
    float scale = isQ ? 0.125f : 1.0f;
    if (!isV){
        // row-major bounce: Cs[m][n], stride 132
        #pragma unroll
        for (int mi = 0; mi < 4; mi++)
            #pragma unroll
            for (int ni = 0; ni < 4; ni++)
                #pragma unroll
                for (int r = 0; r < 4; r++)
                    smem[(wr*64 + mi*16 + quad*4 + r)*132 + wc*64 + ni*16 + l15] =
                        f2bf(scale * acc[mi][ni][r]);
        __syncthreads();
        #pragma unroll
        for (int cc = 0; cc < 8; cc++){
            int chunk = tid + cc*256;           // 0..2047
            int row = chunk >> 4, c8 = (chunk & 15) * 8;
            uint4 v = *(const uint4*)&smem[row*132 + c8];
            if (!isQ){
                *(uint4*)(kbuf + (size_t)(slot*128 + row)*NC + ntile*128 + c8) = v;
            } else {
                int p = perm[tpos + row];
                if (p >= 0)
                    *(uint4*)(qselb + (size_t)p*NC + ntile*128 + c8) = v;
            }
        }
    } else {
        // transposed bounce: Cs[c][t], stride 132
        #pragma unroll
        for (int mi = 0; mi < 4; mi++)
            #pragma unroll
            for (int ni = 0; ni < 4; ni++){
                ushort4 pk;
                pk.x = f2bf(acc[mi][ni][0]);
                pk.y = f2bf(acc[mi][ni][1]);
                pk.z = f2bf(acc[mi][ni][2]);
                pk.w = f2bf(acc[mi][ni][3]);
                *(ushort4*)&smem[(wc*64 + ni*16 + l15)*132 + wr*64 + mi*16 + quad*4] = pk;
            }
        __syncthreads();
        int b = slot >> 3, t0 = (slot & 7)*128;
        int cvBase = (ntile - 8)*128;
        #pragma unroll
        for (int cc = 0; cc < 8; cc++){
            int chunk = tid + cc*256;
            int row = chunk >> 4, c8 = (chunk & 15) * 8;
            uint4 v = *(const uint4*)&smem[row*132 + c8];
            *(uint4*)(vbT + ((size_t)(b*NC + cvBase + row))*TSEQ + t0 + c8) = v;
        }
    }
}

// ---------------------------------------------------------------------------
// O-projection GEMM (grouped), double-buffered staging, raw bf16 out.
// ---------------------------------------------------------------------------
__global__ __launch_bounds__(256)
void gemm_o(const unsigned short* __restrict__ A,
            const unsigned short* __restrict__ Bt,
            unsigned short* __restrict__ osb,
            const int* __restrict__ perm,
            const int* __restrict__ tile_g,
            const int* __restrict__ tile_pos,
            const int* __restrict__ ntiles){
    int ntile = blockIdx.x;
    int slot  = blockIdx.y;
    if (slot >= ntiles[0]) return;
    int g = tile_g[slot];
    const unsigned short* bt = Bt + (size_t)(g & 7) * NC * NC;
    int tpos = tile_pos[slot];

    __shared__ __align__(16) unsigned short smem[4*AB];
    int tid = threadIdx.x;
    int lane = tid & 63, wv = tid >> 6;
    int wr = wv >> 1, wc = wv & 1;
    int quad = lane >> 4, l15 = lane & 15;

    int laneR = lane >> 3;
    int swz = ((lane & 7) ^ (laneR & 7)) * 8;

    const unsigned short* ag[4];
    const unsigned short* bg[4];
    #pragma unroll
    for (int it = 0; it < 4; it++){
        int row = wv*32 + it*8 + laneR;
        int p = perm[tpos + row];
        if (p < 0) p = 0;
        ag[it] = A + (size_t)(p & 1) * MBT * NC + (size_t)(p >> 1) * NC + swz;
        bg[it] = bt + (size_t)(ntile*128 + row) * NC + swz;
    }

    f32x4 acc[4][4];
    #pragma unroll
    for (int i = 0; i < 4; i++)
        #pragma unroll
        for (int j = 0; j < 4; j++) acc[i][j] = (f32x4){0.f,0.f,0.f,0.f};

    #pragma unroll
    for (int it = 0; it < 4; it++){
        gload16(ag[it], &smem[(wv*32 + it*8)*64]);
        gload16(bg[it], &smem[AB + (wv*32 + it*8)*64]);
    }
    int cur = 0;
    for (int kk = 0; kk < NC; kk += 64){
        __syncthreads();
        if (kk + 64 < NC){
            int nb = (cur ^ 1) * 2 * AB;
            #pragma unroll
            for (int it = 0; it < 4; it++){
                gload16(ag[it] + kk + 64, &smem[nb + (wv*32 + it*8)*64]);
                gload16(bg[it] + kk + 64, &smem[nb + AB + (wv*32 + it*8)*64]);
            }
        }
        const unsigned short* As = &smem[cur*2*AB];
        const unsigned short* Bs = &smem[cur*2*AB + AB];
        #pragma unroll
        for (int kh = 0; kh < 2; kh++){
            bf16x8 af[4], bfr[4];
            #pragma unroll
            for (int mi = 0; mi < 4; mi++)
                af[mi]  = *(const bf16x8*)&As[(wr*64 + mi*16 + l15)*64 + (((kh*4 + quad) ^ (l15 & 7))*8)];
            #pragma unroll
            for (int ni = 0; ni < 4; ni++)
                bfr[ni] = *(const bf16x8*)&Bs[(wc*64 + ni*16 + l15)*64 + (((kh*4 + quad) ^ (l15 & 7))*8)];
            #pragma unroll
            for (int mi = 0; mi < 4; mi++)
                #pragma unroll
                for (int ni = 0; ni < 4; ni++)
                    acc[mi][ni] = __builtin_amdgcn_mfma_f32_16x16x32_bf16(af[mi], bfr[ni], acc[mi][ni], 0, 0, 0);
        }
        cur ^= 1;
    }
    __syncthreads();

    #pragma unroll
    for (int mi = 0; mi < 4; mi++)
        #pragma unroll
        for (int ni = 0; ni < 4; ni++)
            #pragma unroll
            for (int r = 0; r < 4; r++)
                smem[(wr*64 + mi*16 + quad*4 + r)*132 + wc*64 + ni*16 + l15] =
                    f2bf(acc[mi][ni][r]);
    __syncthreads();
    #pragma unroll
    for (int cc = 0; cc < 8; cc++){
        int chunk = tid + cc*256;               // 0..2047
        int row = chunk >> 4, c8 = (chunk & 15) * 8;
        int p = perm[tpos + row];
        if (p >= 0){
            uint4 v = *(const uint4*)&smem[row*132 + c8];
            *(uint4*)(osb + ((size_t)(p & 1)*MBT + (p >> 1))*NC + ntile*128 + c8) = v;
        }
    }
}

// out[t][c] = w0[t]*os0[t][c] + w1[t]*os1[t][c]   (os bf16, out fp32)
__global__ __launch_bounds__(256)
void combine(const unsigned short* __restrict__ os, const float* __restrict__ wpair,
             float* __restrict__ out){
    size_t flat = ((size_t)blockIdx.x * 256 + threadIdx.x) * 8;
    int t = (int)(flat >> 10);
    float w0 = wpair[2*t], w1 = wpair[2*t+1];
    bf16x8 a = *(const bf16x8*)(os + flat);
    bf16x8 b = *(const bf16x8*)(os + (size_t)MBT*NC + flat);
    float4 r0, r1;
    r0.x = w0*bf2f((unsigned short)a[0]) + w1*bf2f((unsigned short)b[0]);
    r0.y = w0*bf2f((unsigned short)a[1]) + w1*bf2f((unsigned short)b[1]);
    r0.z = w0*bf2f((unsigned short)a[2]) + w1*bf2f((unsigned short)b[2]);
    r0.w = w0*bf2f((unsigned short)a[3]) + w1*bf2f((unsigned short)b[3]);
    r1.x = w0*bf2f((unsigned short)a[4]) + w1*bf2f((unsigned short)b[4]);
    r1.y = w0*bf2f((unsigned short)a[5]) + w1*bf2f((unsigned short)b[5]);
    r1.z = w0*bf2f((unsigned short)a[6]) + w1*bf2f((unsigned short)b[6]);
    r1.w = w0*bf2f((unsigned short)a[7]) + w1*bf2f((unsigned short)b[7]);
    *(float4*)(out + flat)     = r0;
    *(float4*)(out + flat + 4) = r1;
}

// ---------------------------------------------------------------------------
// Flash attention: fixed-max softmax, wave-uniform mask, packed bf16,
// DOUBLE-BUFFERED K/V DMA staging.  Block = (qpair, b*16+h, s), qb pairing.
// ---------------------------------------------------------------------------
#define KVB 4096   // one K or V staging buffer: 64 x 64 ushorts

__global__ __launch_bounds__(256)
void attn_k(const unsigned short* __restrict__ qsel, const unsigned short* __restrict__ kb,
            const unsigned short* __restrict__ vbT, unsigned short* __restrict__ attnb){
    int b = blockIdx.y >> 4, h = blockIdx.y & 15;
    int s = blockIdx.z;
    int tid = threadIdx.x, lane = tid & 63, wv = tid >> 6;
    int quad = lane >> 4, l15 = lane & 15;
    int laneR = lane >> 3;
    int swz = ((lane & 7) ^ (laneR & 7)) * 8;

    __shared__ __align__(16) unsigned short kv[4*KVB];     // k0,v0,k1,v1
    __shared__ __align__(16) unsigned short pwork[4][32][72];

    #pragma unroll
    for (int half = 0; half < 2; half++){
        int qb = half ? (7 - blockIdx.x) : blockIdx.x;
        int qbase = qb*128 + wv*32;
        int ig[2] = { qbase + l15, qbase + 16 + l15 };

        bf16x8 qf[2][2];
        #pragma unroll
        for (int isub = 0; isub < 2; isub++){
            const unsigned short* qrow = qsel + (((size_t)(b*TSEQ + qbase + isub*16 + l15))*2 + s)*NC + h*DHEAD;
            qf[isub][0] = *(const bf16x8*)(qrow + quad*8);
            qf[isub][1] = *(const bf16x8*)(qrow + 32 + quad*8);
        }

        float lrun[2] = {0.f, 0.f};
        f32x4 oacc[4][2];
        #pragma unroll
        for (int d = 0; d < 4; d++)
            #pragma unroll
            for (int i = 0; i < 2; i++) oacc[d][i] = (f32x4){0.f,0.f,0.f,0.f};

        int njt = qb*2 + 2;
        __syncthreads();     // previous contents (prev half / epilogue) done
        // prologue: jt=0 into buf 0
        #pragma unroll
        for (int it = 0; it < 2; it++){
            int r = wv*16 + it*8 + laneR;
            gload16(kb  + ((size_t)(b*TSEQ + r))*NC + h*DHEAD + swz,
                    &kv[(wv*16 + it*8)*64]);
            gload16(vbT + ((size_t)(b*NC + h*DHEAD + r))*TSEQ + swz,
                    &kv[2*KVB + (wv*16 + it*8)*64]);
        }
        int cur = 0;
        for (int jt = 0; jt < njt; jt++){
            __syncthreads();                    // buf[cur] ready; buf[cur^1] free
            if (jt + 1 < njt){
                int nb = (cur ^ 1) * KVB;
                #pragma unroll
                for (int it = 0; it < 2; it++){
                    int r = wv*16 + it*8 + laneR;
                    gload16(kb  + ((size_t)(b*TSEQ + (jt+1)*64 + r))*NC + h*DHEAD + swz,
                            &kv[nb + (wv*16 + it*8)*64]);
                    gload16(vbT + ((size_t)(b*NC + h*DHEAD + r))*TSEQ + (jt+1)*64 + swz,
                            &kv[nb + 2*KVB + (wv*16 + it*8)*64]);
                }
            }
            const unsigned short* ksh = &kv[cur*KVB];
            const unsigned short* vsh = &kv[cur*KVB + 2*KVB];
            cur ^= 1;

            if (jt*64 > qbase + 31) continue;
            // --- QK^T (S^T orientation); q pre-scaled by 1/8 ---
            f32x4 sac[4][2];
            #pragma unroll
            for (int jsub = 0; jsub < 4; jsub++){
                bf16x8 kf0 = *(const bf16x8*)&ksh[(jsub*16 + l15)*64 + ((quad     ^ (l15 & 7))*8)];
                bf16x8 kf1 = *(const bf16x8*)&ksh[(jsub*16 + l15)*64 + (((4+quad) ^ (l15 & 7))*8)];
                #pragma unroll
                for (int isub = 0; isub < 2; isub++){
                    f32x4 z = (f32x4){0.f,0.f,0.f,0.f};
                    z = __builtin_amdgcn_mfma_f32_16x16x32_bf16(kf0, qf[isub][0], z, 0, 0, 0);
                    z = __builtin_amdgcn_mfma_f32_16x16x32_bf16(kf1, qf[isub][1], z, 0, 0, 0);
                    sac[jsub][isub] = z;
                }
            }
            if (jt*64 + 63 > qbase){          // wave-uniform: only diagonal tiles
                #pragma unroll
                for (int jsub = 0; jsub < 4; jsub++)
                    #pragma unroll
                    for (int r = 0; r < 4; r++){
                        int j = jt*64 + jsub*16 + quad*4 + r;
                        #pragma unroll
                        for (int isub = 0; isub < 2; isub++)
                            if (j > ig[isub]) sac[jsub][isub][r] = -1e30f;
                    }
            }
            // --- exp (fixed max), sum, pack to bf16 ---
            #pragma unroll
            for (int isub = 0; isub < 2; isub++){
                float rs = 0.f;
                #pragma unroll
                for (int jsub = 0; jsub < 4; jsub++){
                    float p0 = __expf(sac[jsub][isub][0]);
                    float p1 = __expf(sac[jsub][isub][1]);
                    float p2 = __expf(sac[jsub][isub][2]);
                    float p3 = __expf(sac[jsub][isub][3]);
                    rs += (p0 + p1) + (p2 + p3);
                    uint2 pk;
                    pk.x = pk2bf(p0, p1);
                    pk.y = pk2bf(p2, p3);
                    *(uint2*)&pwork[wv][isub*16 + l15][jsub*16 + quad*4] = pk;
                }
                rs += __shfl_xor(rs, 16, 64);
                rs += __shfl_xor(rs, 32, 64);
                lrun[isub] += rs;
            }
            // --- read P as B-operand (same wave, in-order LDS) ---
            bf16x8 pf[2][2];
            #pragma unroll
            for (int kh = 0; kh < 2; kh++)
                #pragma unroll
                for (int isub = 0; isub < 2; isub++)
                    pf[kh][isub] = *(const bf16x8*)&pwork[wv][isub*16 + l15][kh*32 + quad*8];
            // --- PV: O^T += V^T * P^T ---
            #pragma unroll
            for (int dsub = 0; dsub < 4; dsub++){
                bf16x8 vf0 = *(const bf16x8*)&vsh[(dsub*16 + l15)*64 + ((quad     ^ (l15 & 7))*8)];
                bf16x8 vf1 = *(const bf16x8*)&vsh[(dsub*16 + l15)*64 + (((4+quad) ^ (l15 & 7))*8)];
                #pragma unroll
                for (int isub = 0; isub < 2; isub++){
                    oacc[dsub][isub] = __builtin_amdgcn_mfma_f32_16x16x32_bf16(vf0, pf[0][isub], oacc[dsub][isub], 0, 0, 0);
                    oacc[dsub][isub] = __builtin_amdgcn_mfma_f32_16x16x32_bf16(vf1, pf[1][isub], oacc[dsub][isub], 0, 0, 0);
                }
            }
        }

        // epilogue: normalize, transpose via per-wave LDS, coalesced stores
        float inv[2] = { 1.f / lrun[0], 1.f / lrun[1] };
        #pragma unroll
        for (int dsub = 0; dsub < 4; dsub++)
            #pragma unroll
            for (int isub = 0; isub < 2; isub++){
                uint2 ov;
                ov.x = pk2bf(oacc[dsub][isub][0] * inv[isub], oacc[dsub][isub][1] * inv[isub]);
                ov.y = pk2bf(oacc[dsub][isub][2] * inv[isub], oacc[dsub][isub][3] * inv[isub]);
                *(uint2*)&pwork[wv][isub*16 + l15][dsub*16 + quad*4] = ov;
            }
        #pragma unroll
        for (int rr = 0; rr < 4; rr++){
            int idx = rr*64 + lane;
            int il = idx >> 3, cc = (idx & 7) * 8;
            int t = qb*128 + wv*32 + il;
            *(uint4*)(attnb + (size_t)s*MBT*NC + ((size_t)(b*TSEQ + t))*NC + h*DHEAD + cc) =
                *(const uint4*)&pwork[wv][il][cc];
        }
    }
}

// ---------------------------------------------------------------------------
extern "C" void kernel_launch(void* const* d_in, const int* in_sizes, int n_in,
                              void* d_out, int out_size, void* d_ws, size_t ws_size,
                              hipStream_t stream){
    (void)in_sizes; (void)n_in; (void)out_size; (void)ws_size;
    const float* x     = (const float*)d_in[0];
    const float* noise = (const float*)d_in[1];
    const float* Wk    = (const float*)d_in[2];
    const float* Wv    = (const float*)d_in[3];
    const float* Wq    = (const float*)d_in[4];
    const float* Wo    = (const float*)d_in[5];
    const float* Wg    = (const float*)d_in[6];
    const float* Wn    = (const float*)d_in[7];
    float* out = (float*)d_out;

    char* ws = (char*)d_ws;
    size_t off = 0;
    auto alloc = [&](size_t bytes) -> void* {
        void* p = ws + off;
        off += (bytes + 255) & ~(size_t)255;
        return p;
    };
    unsigned short* xb    = (unsigned short*)alloc((size_t)MBT*NC*2);
    unsigned short* vbufT = (unsigned short*)alloc((size_t)MBT*NC*2);
    unsigned short* kbuf  = (unsigned short*)alloc((size_t)MBT*NC*2);
    unsigned short* qselb = (unsigned short*)alloc((size_t)MBT*2*NC*2);
    unsigned short* attnb = (unsigned short*)alloc((size_t)2*MBT*NC*2);
    unsigned short* Wkvt  = (unsigned short*)alloc((size_t)2*NC*NC*2);
    unsigned short* Wqt   = (unsigned short*)alloc((size_t)NEXP*NC*NC*2);
    unsigned short* Wot   = (unsigned short*)alloc((size_t)NEXP*NC*NC*2);
    int*   epair   = (int*)alloc(2*MBT*4);
    float* wpair   = (float*)alloc(2*MBT*4);
    int*   perm    = (int*)alloc(PERM_CAP*4);
    int*   cursor  = (int*)alloc(16*4);
    int*   tile_g  = (int*)alloc(MAXTILES*4);
    int*   tile_pos= (int*)alloc(MAXTILES*4);
    int*   ntiles  = (int*)alloc(4);

    // os[2][MBT][NC] bf16 aliases qselb (dead after attn; same size)
    unsigned short* osb = qselb;

    prep_gate<<<dim3(32,32,19), dim3(32,8), 0, stream>>>(Wk, Wv, Wq, Wo, Wkvt, Wqt, Wot,
                                                         x, noise, Wg, Wn, epair, wpair, xb);
    group_build<<<1, 256, 0, stream>>>(epair, cursor, tile_g, tile_pos, ntiles, perm);
    fill_perm<<<32, 256, 0, stream>>>(epair, cursor, perm);

    gemm_fused<<<1280, 256, 0, stream>>>(xb, Wkvt, Wqt, kbuf, vbufT, qselb,
                                         perm, tile_g, tile_pos, ntiles);

    attn_k<<<dim3(4,64,2), 256, 0, stream>>>(qselb, kbuf, vbufT, attnb);

    gemm_o<<<dim3(8,MAXTILES), 256, 0, stream>>>(attnb, Wot, osb, perm, tile_g, tile_pos, ntiles);
    combine<<<2048, 256, 0, stream>>>(osb, wpair, out);
}